// Round 1
// 3291.359 us; speedup vs baseline: 1.1401x; 1.1401x over previous
//
#include <hip/hip_runtime.h>
#include <hip/hip_bf16.h>
#include <stdint.h>

#define D 128
#define NITER 8

typedef __bf16 bf16_t;
typedef __bf16 bf16x8 __attribute__((ext_vector_type(8)));
typedef float f32x4 __attribute__((ext_vector_type(4)));

__device__ __forceinline__ f32x4 mfma_bf16(bf16x8 a, bf16x8 b, f32x4 c) {
    return __builtin_amdgcn_mfma_f32_16x16x32_bf16(a, b, c, 0, 0, 0);
}
__device__ __forceinline__ float sigmoidf_fast(float x) { return 1.0f / (1.0f + __expf(-x)); }
__device__ __forceinline__ float tanhf_fast(float x) {
    float e = __expf(-2.0f * fabsf(x));
    float t = (1.0f - e) / (1.0f + e);
    return copysignf(t, x);
}

// ---- dtype detection: flag=1 if buffer holds packed bf16, 0 if fp32 ----
__global__ void detect_kernel(const unsigned* __restrict__ x, int* flag) {
    __shared__ int hits;
    if (threadIdx.x == 0) hits = 0;
    __syncthreads();
    unsigned v = x[threadIdx.x];
    unsigned lo = v & 0xffffu;
    unsigned ex = (lo >> 7) & 0xff;
    if (ex >= 110 && ex <= 132) atomicAdd(&hits, 1);
    __syncthreads();
    if (threadIdx.x == 0) *flag = (hits > 192) ? 1 : 0;
}

// ---- batched canonicalize: all 20 float params -> bf16 in ONE launch ----
struct ConvArgs {
    const void* src[20];
    bf16_t* dst[20];
    int n[20];
};
__global__ __launch_bounds__(256) void conv_all_kernel(ConvArgs a, const int* __restrict__ flag) {
    const int j = blockIdx.y;
    const int i = blockIdx.x * 256 + threadIdx.x;
    if (i >= a.n[j]) return;
    if (*flag) a.dst[j][i] = ((const bf16_t*)a.src[j])[i];
    else       a.dst[j][i] = (bf16_t)((const float*)a.src[j])[i];
}

// copy both initial embeddings -> output slot 0, preserving dtype
__global__ void outcopy2_kernel(const void* __restrict__ srcL, const void* __restrict__ srcC,
                                void* __restrict__ dstbase, size_t c_base,
                                int nL, int nC, const int* __restrict__ flag) {
    int i = blockIdx.x * 256 + threadIdx.x;
    const int isb = *flag;
    if (i < nL) {
        if (isb) ((uint16_t*)dstbase)[i] = ((const uint16_t*)srcL)[i];
        else     ((float*)dstbase)[i]    = ((const float*)srcL)[i];
    } else {
        int k = i - nL;
        if (k >= nC) return;
        if (isb) ((uint16_t*)dstbase)[c_base + k] = ((const uint16_t*)srcC)[k];
        else     ((float*)dstbase)[c_base + k]    = ((const float*)srcC)[k];
    }
}

// ---- dtype-aware element access helpers ----
__device__ __forceinline__ const void* slot_ptr(const void* base, size_t off_elems, int isb) {
    return isb ? (const void*)((const bf16_t*)base + off_elems)
               : (const void*)((const float*)base + off_elems);
}
__device__ __forceinline__ bf16x8 load_h8(const void* h, size_t off, int isb) {
    if (isb) return *reinterpret_cast<const bf16x8*>((const bf16_t*)h + off);
    const float* f = (const float*)h + off;
    f32x4 a = *reinterpret_cast<const f32x4*>(f);
    f32x4 b = *reinterpret_cast<const f32x4*>(f + 4);
    bf16x8 r;
    r[0] = (bf16_t)a[0]; r[1] = (bf16_t)a[1]; r[2] = (bf16_t)a[2]; r[3] = (bf16_t)a[3];
    r[4] = (bf16_t)b[0]; r[5] = (bf16_t)b[1]; r[6] = (bf16_t)b[2]; r[7] = (bf16_t)b[3];
    return r;
}
__device__ __forceinline__ float load_h1(const void* h, size_t off, int isb) {
    return isb ? (float)((const bf16_t*)h)[off] : ((const float*)h)[off];
}
__device__ __forceinline__ void store_h1(void* o, size_t off, float v, int isb) {
    if (isb) ((bf16_t*)o)[off] = (bf16_t)v;
    else     ((float*)o)[off] = v;
}

// ---------------- CSR build ----------------
__global__ void zero2_kernel(int* a, int na, int* b, int nb) {
    int i = blockIdx.x * 256 + threadIdx.x;
    if (i < na) a[i] = 0;
    if (i < nb) b[i] = 0;
}
__global__ void count_kernel(const int* __restrict__ ce, const int* __restrict__ le,
                             int E, int* cnt_c, int* cnt_l) {
    int i = blockIdx.x * 256 + threadIdx.x;
    if (i < E) {
        atomicAdd(&cnt_c[ce[i]], 1);
        atomicAdd(&cnt_l[le[i]], 1);
    }
}
__device__ __forceinline__ void scan_body(const int* __restrict__ counts,
                                          int* __restrict__ row_ptr,
                                          int* __restrict__ cursor, int n) {
    __shared__ __align__(16) int sums[256];
    __shared__ __align__(16) int pre[257];
    const int tid = threadIdx.x;
    const int chunk = (n + 255) >> 8;
    int start = tid * chunk, end = start + chunk;
    if (start > n) start = n;
    if (end > n) end = n;
    int s = 0;
    for (int i = start; i < end; ++i) s += counts[i];
    sums[tid] = s;
    __syncthreads();
    if (tid == 0) {
        int acc = 0;
        for (int i = 0; i < 256; ++i) { pre[i] = acc; acc += sums[i]; }
        pre[256] = acc;
    }
    __syncthreads();
    int off = pre[tid];
    for (int i = start; i < end; ++i) {
        row_ptr[i] = off;
        cursor[i] = off;
        off += counts[i];
    }
    if (tid == 0) row_ptr[n] = pre[256];
}
__global__ __launch_bounds__(256) void scan2_kernel(
    const int* cnt_c, int* ptr_c, int* cur_c, int C,
    const int* cnt_l, int* ptr_l, int* cur_l, int L) {
    if (blockIdx.x == 0) scan_body(cnt_c, ptr_c, cur_c, C);
    else                 scan_body(cnt_l, ptr_l, cur_l, L);
}
__global__ void fill2_kernel(const int* __restrict__ ce, const int* __restrict__ le,
                             int E, int* cur_c, int* cur_l,
                             int* src_c, int* src_l) {
    int i = blockIdx.x * 256 + threadIdx.x;
    if (i < E) {
        int p = atomicAdd(&cur_c[ce[i]], 1);
        src_c[p] = le[i];
        int q = atomicAdd(&cur_l[le[i]], 1);
        src_l[q] = ce[i];
    }
}

// ---------------- fused 2-layer MLP body ----------------
__device__ __forceinline__ void mlp_body(
    const void* __restrict__ xbase, size_t x_off, const bf16_t* __restrict__ W0,
    const bf16_t* __restrict__ b0, const bf16_t* __restrict__ W1,
    const bf16_t* __restrict__ b1, bf16_t* __restrict__ out, int N,
    bool swap, int blk, int isb)
{
    __shared__ __align__(16) bf16_t hbuf[4][16][136];
    const void* x = slot_ptr(xbase, x_off, isb);
    const int tid = threadIdx.x;
    const int wave = tid >> 6, lane = tid & 63;
    const int m = lane & 15, q = lane >> 4;
    const int rowbase = blk * 64 + wave * 16;
    int lrow = rowbase + m;
    if (lrow > N - 1) lrow = N - 1;
    const int arow = swap ? (lrow ^ 1) : lrow;

    bf16x8 afrag[4];
    #pragma unroll
    for (int k0 = 0; k0 < 4; ++k0)
        afrag[k0] = load_h8(x, (size_t)arow * D + k0 * 32 + q * 8, isb);

    #pragma unroll
    for (int c = 0; c < 8; ++c) {
        f32x4 acc = {0.f, 0.f, 0.f, 0.f};
        #pragma unroll
        for (int k0 = 0; k0 < 4; ++k0) {
            bf16x8 b = *reinterpret_cast<const bf16x8*>(W0 + (size_t)(c * 16 + m) * D + k0 * 32 + q * 8);
            acc = mfma_bf16(afrag[k0], b, acc);
        }
        const float bias = (float)b0[c * 16 + m];
        #pragma unroll
        for (int r = 0; r < 4; ++r) {
            float v = acc[r] + bias;
            hbuf[wave][q * 4 + r][c * 16 + m] = (bf16_t)(v > 0.f ? v : 0.f);
        }
    }
    __syncthreads();

    bf16x8 hfrag[4];
    #pragma unroll
    for (int k0 = 0; k0 < 4; ++k0)
        hfrag[k0] = *reinterpret_cast<const bf16x8*>(&hbuf[wave][m][k0 * 32 + q * 8]);

    #pragma unroll
    for (int c = 0; c < 8; ++c) {
        f32x4 acc = {0.f, 0.f, 0.f, 0.f};
        #pragma unroll
        for (int k0 = 0; k0 < 4; ++k0) {
            bf16x8 b = *reinterpret_cast<const bf16x8*>(W1 + (size_t)(c * 16 + m) * D + k0 * 32 + q * 8);
            acc = mfma_bf16(hfrag[k0], b, acc);
        }
        const float bias = (float)b1[c * 16 + m];
        #pragma unroll
        for (int r = 0; r < 4; ++r) {
            int orow = rowbase + q * 4 + r;
            if (orow < N) out[(size_t)orow * D + c * 16 + m] = (bf16_t)(acc[r] + bias);
        }
    }
}

// merged: l2l(L,swap) | l2c(L) | c2l(C) — all independent, one launch
__global__ __launch_bounds__(256) void mlp3_kernel(
    const void* __restrict__ xbase, size_t hl_off, size_t hc_off,
    const bf16_t* __restrict__ W0c2, const bf16_t* __restrict__ b0c2,
    const bf16_t* __restrict__ W1c2, const bf16_t* __restrict__ b1c2, bf16_t* __restrict__ outC2, // l2l
    const bf16_t* __restrict__ W0a, const bf16_t* __restrict__ b0a,
    const bf16_t* __restrict__ W1a, const bf16_t* __restrict__ b1a, bf16_t* __restrict__ outA,    // l2c
    const bf16_t* __restrict__ W0b, const bf16_t* __restrict__ b0b,
    const bf16_t* __restrict__ W1b, const bf16_t* __restrict__ b1b, bf16_t* __restrict__ outB,    // c2l
    int L, int C, int nbL, const int* __restrict__ flag)
{
    const int isb = *flag;
    const int b = blockIdx.x;
    if (b < nbL) {
        mlp_body(xbase, hl_off, W0c2, b0c2, W1c2, b1c2, outC2, L, true, b, isb);
    } else if (b < 2 * nbL) {
        mlp_body(xbase, hl_off, W0a, b0a, W1a, b1a, outA, L, false, b - nbL, isb);
    } else {
        mlp_body(xbase, hc_off, W0b, b0b, W1b, b1b, outB, C, false, b - 2 * nbL, isb);
    }
}

// ---------------- CSR segment sum body (2-deep src prefetch) ----------------
__device__ __forceinline__ void seg_body(
    const bf16_t* __restrict__ msg, const int* __restrict__ row_ptr,
    const int* __restrict__ srcs, bf16_t* __restrict__ out, int Ndst,
    int Nsrc, int E, int blk)
{
    const int wave = threadIdx.x >> 6, lane = threadIdx.x & 63;
    const int dst = blk * 4 + wave;
    if (dst >= Ndst) return;
    int s = row_ptr[dst], e = row_ptr[dst + 1];
    s = s < 0 ? 0 : (s > E ? E : s);
    e = e < s ? s : (e > E ? E : e);
    float a0 = 0.f, a1 = 0.f;
    int srcn = (s < e) ? srcs[s] : 0;
    for (int i = s; i < e; ++i) {
        int src = srcn;
        if (i + 1 < e) srcn = srcs[i + 1];
        src = src < 0 ? 0 : (src >= Nsrc ? Nsrc - 1 : src);
        unsigned v = *reinterpret_cast<const unsigned*>(msg + (size_t)src * D + lane * 2);
        union { unsigned u; float f; } lo, hi;
        lo.u = v << 16;
        hi.u = v & 0xffff0000u;
        a0 += lo.f;
        a1 += hi.f;
    }
    union { unsigned u; bf16_t b[2]; } pk;
    pk.b[0] = (bf16_t)a0;
    pk.b[1] = (bf16_t)a1;
    *reinterpret_cast<unsigned*>(out + (size_t)dst * D + lane * 2) = pk.u;
}

// merged: aggregate l2c msgs -> clauses | c2l msgs -> literals
__global__ __launch_bounds__(256) void seg2_kernel(
    const bf16_t* __restrict__ msgA, const int* __restrict__ ptr_c,
    const int* __restrict__ src_c, bf16_t* __restrict__ aggC, int C, int L,
    const bf16_t* __restrict__ msgB, const int* __restrict__ ptr_l,
    const int* __restrict__ src_l, bf16_t* __restrict__ aggL,
    int E, int sbC)
{
    const int b = blockIdx.x;
    if (b < sbC) seg_body(msgA, ptr_c, src_c, aggC, C, L, E, b);
    else         seg_body(msgB, ptr_l, src_l, aggL, L, C, E, b - sbC);
}

// ---------------- fused GRU body ----------------
template<int KX>
__device__ __forceinline__ void gru_body(
    const bf16_t* __restrict__ x0, const bf16_t* __restrict__ x1,
    const void* __restrict__ slotbase, size_t h_off, size_t o_off,
    const bf16_t* __restrict__ Wih, const bf16_t* __restrict__ Whh,
    const bf16_t* __restrict__ bih, const bf16_t* __restrict__ bhh,
    int N, int blk, int isb)
{
    const void* h = slot_ptr(slotbase, h_off, isb);
    void* outp = (void*)slot_ptr(slotbase, o_off, isb);
    const int tid = threadIdx.x;
    const int wave = tid >> 6, lane = tid & 63;
    const int m = lane & 15, q = lane >> 4;
    const int rowbase = blk * 64 + wave * 16;
    int lrow = rowbase + m;
    if (lrow > N - 1) lrow = N - 1;

    constexpr int NKX = KX / 32;
    bf16x8 xfrag[NKX];
    #pragma unroll
    for (int kk = 0; kk < NKX; ++kk) {
        const bf16_t* p = (kk < 4) ? (x0 + (size_t)lrow * D + kk * 32)
                                   : (x1 + (size_t)lrow * D + (kk - 4) * 32);
        xfrag[kk] = *reinterpret_cast<const bf16x8*>(p + q * 8);
    }
    bf16x8 hfrag[4];
    #pragma unroll
    for (int kk = 0; kk < 4; ++kk)
        hfrag[kk] = load_h8(h, (size_t)lrow * D + kk * 32 + q * 8, isb);

    #pragma unroll
    for (int c = 0; c < 8; ++c) {
        f32x4 gi[3], gh[3];
        #pragma unroll
        for (int p = 0; p < 3; ++p) {
            gi[p] = {0.f, 0.f, 0.f, 0.f};
            gh[p] = {0.f, 0.f, 0.f, 0.f};
        }
        #pragma unroll
        for (int p = 0; p < 3; ++p) {
            const bf16_t* wi = Wih + (size_t)(p * 128 + c * 16 + m) * KX + q * 8;
            #pragma unroll
            for (int kk = 0; kk < NKX; ++kk)
                gi[p] = mfma_bf16(xfrag[kk], *reinterpret_cast<const bf16x8*>(wi + kk * 32), gi[p]);
            const bf16_t* wh = Whh + (size_t)(p * 128 + c * 16 + m) * D + q * 8;
            #pragma unroll
            for (int kk = 0; kk < 4; ++kk)
                gh[p] = mfma_bf16(hfrag[kk], *reinterpret_cast<const bf16x8*>(wh + kk * 32), gh[p]);
        }
        const int col = c * 16 + m;
        const float bi0 = (float)bih[col], bi1 = (float)bih[128 + col], bi2 = (float)bih[256 + col];
        const float bh0 = (float)bhh[col], bh1 = (float)bhh[128 + col], bh2 = (float)bhh[256 + col];
        #pragma unroll
        for (int r = 0; r < 4; ++r) {
            int orow = rowbase + q * 4 + r;
            bool valid = orow < N;
            float hold = valid ? load_h1(h, (size_t)orow * D + col, isb) : 0.f;
            float rg = sigmoidf_fast(gi[0][r] + bi0 + gh[0][r] + bh0);
            float zg = sigmoidf_fast(gi[1][r] + bi1 + gh[1][r] + bh1);
            float ng = tanhf_fast(gi[2][r] + bi2 + rg * (gh[2][r] + bh2));
            float hv = (1.f - zg) * ng + zg * hold;
            if (valid) store_h1(outp, (size_t)orow * D + col, hv, isb);
        }
    }
}

// merged: literal GRU (KX=256, L rows) | clause GRU (KX=128, C rows)
__global__ __launch_bounds__(256) void gru2_kernel(
    const bf16_t* __restrict__ aggL, const bf16_t* __restrict__ msgC,
    const void* __restrict__ slotbase,
    size_t hl_off, size_t hl_new_off, size_t hc_off, size_t hc_new_off,
    const bf16_t* __restrict__ WihL, const bf16_t* __restrict__ WhhL,
    const bf16_t* __restrict__ bihL, const bf16_t* __restrict__ bhhL,
    const bf16_t* __restrict__ aggC,
    const bf16_t* __restrict__ WihC, const bf16_t* __restrict__ WhhC,
    const bf16_t* __restrict__ bihC, const bf16_t* __restrict__ bhhC,
    int L, int C, int nbL, const int* __restrict__ flag)
{
    const int isb = *flag;
    const int b = blockIdx.x;
    if (b < nbL) {
        gru_body<256>(aggL, msgC, slotbase, hl_off, hl_new_off,
                      WihL, WhhL, bihL, bhhL, L, b, isb);
    } else {
        gru_body<128>(aggC, aggC, slotbase, hc_off, hc_new_off,
                      WihC, WhhC, bihC, bhhC, C, b - nbL, isb);
    }
}

extern "C" void kernel_launch(void* const* d_in, const int* in_sizes, int n_in,
                              void* d_out, int out_size, void* d_ws, size_t ws_size,
                              hipStream_t stream) {
    const int E = in_sizes[2];
    const int L = in_sizes[4] / D;
    const int C = in_sizes[5] / D;

    const int* l_edge = (const int*)d_in[2];
    const int* c_edge = (const int*)d_in[3];

    // ---- workspace carve ----
    char* w = (char*)d_ws;
    auto alloc = [&](size_t bytes) {
        void* p = (void*)w;
        w += (bytes + 255) & ~(size_t)255;
        return p;
    };
    int* flag  = (int*)alloc(4);
    int* ptr_c = (int*)alloc((size_t)(C + 1) * 4);
    int* ptr_l = (int*)alloc((size_t)(L + 1) * 4);
    int* cnt_c = (int*)alloc((size_t)C * 4);
    int* cnt_l = (int*)alloc((size_t)L * 4);
    int* cur_c = (int*)alloc((size_t)C * 4);
    int* cur_l = (int*)alloc((size_t)L * 4);
    int* src_c = (int*)alloc((size_t)E * 4);
    int* src_l = (int*)alloc((size_t)E * 4);

    bf16_t* wc[26];
    for (int i = 6; i < 26; ++i)
        wc[i] = (bf16_t*)alloc((size_t)in_sizes[i] * 2);

    bf16_t* msgA = (bf16_t*)alloc((size_t)L * D * 2);   // l2c messages
    bf16_t* msgB = (bf16_t*)alloc((size_t)C * D * 2);   // c2l messages
    bf16_t* msgC = (bf16_t*)alloc((size_t)L * D * 2);   // l2l messages
    bf16_t* aggC = (bf16_t*)alloc((size_t)C * D * 2);   // l2c aggregated at clauses
    bf16_t* aggL = (bf16_t*)alloc((size_t)L * D * 2);   // c2l aggregated at literals

    // ---- dtype flag + canonicalize all 20 params in one launch ----
    detect_kernel<<<1, 256, 0, stream>>>((const unsigned*)d_in[4], flag);
    ConvArgs ca;
    int maxn = 0;
    for (int i = 6; i < 26; ++i) {
        ca.src[i - 6] = d_in[i];
        ca.dst[i - 6] = wc[i];
        ca.n[i - 6] = in_sizes[i];
        if (in_sizes[i] > maxn) maxn = in_sizes[i];
    }
    conv_all_kernel<<<dim3((maxn + 255) / 256, 20), 256, 0, stream>>>(ca, flag);

    // ---- CSR build (merged launches) ----
    int zt = (C > L ? C : L);
    zero2_kernel<<<(zt + 255) / 256, 256, 0, stream>>>(cnt_c, C, cnt_l, L);
    count_kernel<<<(E + 255) / 256, 256, 0, stream>>>(c_edge, l_edge, E, cnt_c, cnt_l);
    scan2_kernel<<<2, 256, 0, stream>>>(cnt_c, ptr_c, cur_c, C, cnt_l, ptr_l, cur_l, L);
    fill2_kernel<<<(E + 255) / 256, 256, 0, stream>>>(c_edge, l_edge, E, cur_c, cur_l, src_c, src_l);

    // ---- slot 0 = initial embeddings ----
    const size_t LD = (size_t)L * D, CD = (size_t)C * D;
    const size_t c_base = 9 * LD;
    outcopy2_kernel<<<((int)(LD + CD) + 255) / 256, 256, 0, stream>>>(
        d_in[4], d_in[5], d_out, c_base, (int)LD, (int)CD, flag);

    const int NBL = (L + 63) / 64;   // MLP/GRU blocks for L rows
    const int NBC = (C + 63) / 64;
    const int SBC = (C + 3) / 4;     // segsum blocks (4 dst rows / block)
    const int SBL = (L + 3) / 4;

    for (int t = 1; t <= NITER; ++t) {
        const size_t hl = (size_t)(t - 1) * LD, hl_new = (size_t)t * LD;
        const size_t hc = c_base + (size_t)(t - 1) * CD, hc_new = c_base + (size_t)t * CD;

        // all three MLPs are independent (read only OLD h slots) -> one launch
        mlp3_kernel<<<2 * NBL + NBC, 256, 0, stream>>>(
            d_out, hl, hc,
            wc[14], wc[15], wc[16], wc[17], msgC,   // l2l (swap)
            wc[6],  wc[7],  wc[8],  wc[9],  msgA,   // l2c
            wc[10], wc[11], wc[12], wc[13], msgB,   // c2l
            L, C, NBL, flag);

        // both segment-sums independent -> one launch
        seg2_kernel<<<SBC + SBL, 256, 0, stream>>>(
            msgA, ptr_c, src_c, aggC, C, L,
            msgB, ptr_l, src_l, aggL, E, SBC);

        // both GRUs independent -> one launch
        gru2_kernel<<<NBL + NBC, 256, 0, stream>>>(
            aggL, msgC, d_out, hl, hl_new, hc, hc_new,
            wc[22], wc[23], wc[24], wc[25],
            aggC, wc[18], wc[19], wc[20], wc[21],
            L, C, NBL, flag);
    }
}